// Round 1
// baseline (749.826 us; speedup 1.0000x reference)
//
#include <hip/hip_runtime.h>
#include <math.h>

#define NN 100000
#define EE 1600000
#define GG 100
#define DIN 128
#define F1 128
#define FOUT 16

#define C1CAP 16384
#define C0CAP 49152
#define L1CAP 262144
#define L2CAP 32768

// ---- workspace layout (offsets in 4-byte words) ----
// zeroed region first (single memset):
#define O_CNT      0                        // 8 ints: [0]=c1,[1]=c0,[2]=l1,[3]=l2
#define O_FLAG1    (O_CNT + 8)              // int[NN]
#define O_FLAG0    (O_FLAG1 + NN)           // int[NN]
#define O_ISROOT   (O_FLAG0 + NN)           // int[NN]
#define O_S1       (O_ISROOT + NN)          // float[C1CAP*4]
#define O_S2       (O_S1 + C1CAP*4)         // float[C1CAP]
#define O_OUT1     (O_S2 + C1CAP)           // float[C1CAP*F1]
#define O_OUT2     (O_OUT1 + C1CAP*F1)      // float[C1CAP*FOUT]
#define O_ZEND     (O_OUT2 + C1CAP*FOUT)
// initialized by gat_init / written before read:
#define O_ROOT     (O_ZEND)                 // int[GG]
#define O_MAP1     (O_ROOT + GG)            // int[NN]
#define O_MAP0     (O_MAP1 + NN)            // int[NN]
#define O_LIST1    (O_MAP0 + NN)            // int[C1CAP]
#define O_LIST0    (O_LIST1 + C1CAP)        // int[C0CAP]
#define O_L1       (O_LIST0 + C0CAP)        // int[L1CAP*2] (src,dst pairs)
#define O_L2       (O_L1 + L1CAP*2)         // int[L2CAP*2]
#define O_H1       (O_L2 + L2CAP*2)         // float[C0CAP*F1]
#define O_A1S      (O_H1 + C0CAP*F1)        // float[C0CAP*4]
#define O_A1D      (O_A1S + C0CAP*4)        // float[C0CAP*4]
#define O_M1       (O_A1D + C0CAP*4)        // float[C1CAP*4]
#define O_H2       (O_M1 + C1CAP*4)         // float[C1CAP*FOUT]
#define O_A2S      (O_H2 + C1CAP*FOUT)      // float[C1CAP]
#define O_A2D      (O_A2S + C1CAP)          // float[C1CAP]
#define O_M2       (O_A2D + C1CAP)          // float[C1CAP]
#define O_END      (O_M2 + C1CAP)

__device__ __forceinline__ void atomicMaxF(float* a, float v) {
  if (v >= 0.f) atomicMax((int*)a, __float_as_int(v));
  else          atomicMin((unsigned int*)a, __float_as_uint(v));
}

__device__ __forceinline__ void claim1(int* ws, int node) {
  if (atomicCAS(&ws[O_FLAG1 + node], 0, 1) == 0) {
    int idx = atomicAdd(&ws[O_CNT + 0], 1);
    if (idx < C1CAP) { ws[O_MAP1 + node] = idx; ws[O_LIST1 + idx] = node; }
  }
}
__device__ __forceinline__ void claim0(int* ws, int node) {
  if (atomicCAS(&ws[O_FLAG0 + node], 0, 1) == 0) {
    int idx = atomicAdd(&ws[O_CNT + 1], 1);
    if (idx < C0CAP) { ws[O_MAP0 + node] = idx; ws[O_LIST0 + idx] = node; }
  }
}
__device__ __forceinline__ void appendL1(int* ws, int s, int d) {
  int idx = atomicAdd(&ws[O_CNT + 2], 1);
  if (idx < L1CAP) { ws[O_L1 + 2*idx] = s; ws[O_L1 + 2*idx + 1] = d; }
}
__device__ __forceinline__ void appendL2(int* ws, int s, int d) {
  int idx = atomicAdd(&ws[O_CNT + 3], 1);
  if (idx < L2CAP) { ws[O_L2 + 2*idx] = s; ws[O_L2 + 2*idx + 1] = d; }
}

__global__ void gat_init(int* ws) {
  int i = blockIdx.x * blockDim.x + threadIdx.x;
  float* m1 = (float*)(ws + O_M1);
  float* m2 = (float*)(ws + O_M2);
  if (i < GG) ws[O_ROOT + i] = 0x7FFFFFFF;
  if (i < C1CAP * 4) m1[i] = -INFINITY;
  if (i < C1CAP) m2[i] = -INFINITY;
}

// root of group g = min node index with x[:,0]==0 in that group
__global__ void gat_roots(const float* __restrict__ x, const int* __restrict__ batch, int* ws) {
  int i = blockIdx.x * blockDim.x + threadIdx.x;
  if (i >= NN) return;
  if (x[(size_t)i * DIN] == 0.f) atomicMin(&ws[O_ROOT + batch[i]], i);
}

__global__ void gat_mark_roots(int* ws) {
  int g = blockIdx.x * blockDim.x + threadIdx.x;
  if (g >= GG) return;
  int r = ws[O_ROOT + g];
  if (r < NN) {
    ws[O_ISROOT + r] = 1;
    claim1(ws, r);
    appendL2(ws, r, r);   // layer-2 self-loop
  }
}

// scan all edges: keep those into roots (layer-2 edge list), mark their srcs as need1
__global__ void gat_scan2(const int* __restrict__ ei, int* ws) {
  int e = blockIdx.x * blockDim.x + threadIdx.x;
  if (e >= EE) return;
  int d = ei[EE + e];
  if (ws[O_ISROOT + d]) {
    int s = ei[e];
    appendL2(ws, s, d);
    claim1(ws, s);
  }
}

// every need1 node gets a layer-1 self-loop and needs its own h1lin
__global__ void gat_selfloop1(int* ws) {
  int c1 = ws[O_CNT + 0]; if (c1 > C1CAP) c1 = C1CAP;
  for (int i = blockIdx.x * blockDim.x + threadIdx.x; i < c1; i += gridDim.x * blockDim.x) {
    int v = ws[O_LIST1 + i];
    appendL1(ws, v, v);
    claim0(ws, v);
  }
}

// scan all edges: keep those into need1 nodes (layer-1 edge list), mark srcs as need0
__global__ void gat_scan1(const int* __restrict__ ei, int* ws) {
  int e = blockIdx.x * blockDim.x + threadIdx.x;
  if (e >= EE) return;
  int d = ei[EE + e];
  if (ws[O_FLAG1 + d]) {
    int s = ei[e];
    appendL1(ws, s, d);
    claim0(ws, s);
  }
}

// h1lin = x@W1 at need0 nodes; also a_src1/a_dst1 per head
__global__ void gat_h1lin(const float* __restrict__ x, const float* __restrict__ W1,
                          const float* __restrict__ att_s1, const float* __restrict__ att_d1,
                          int* ws) {
  __shared__ float W1s[DIN * F1];   // 64 KiB
  __shared__ float xs[DIN];
  __shared__ float hs[F1];
  int t = threadIdx.x;  // 128
  for (int i = t; i < DIN * F1; i += blockDim.x) W1s[i] = W1[i];
  __syncthreads();
  int c0 = ws[O_CNT + 1]; if (c0 > C0CAP) c0 = C0CAP;
  float* h1  = (float*)(ws + O_H1);
  float* a1s = (float*)(ws + O_A1S);
  float* a1d = (float*)(ws + O_A1D);
  for (int ci = blockIdx.x; ci < c0; ci += gridDim.x) {
    int v = ws[O_LIST0 + ci];
    xs[t] = x[(size_t)v * DIN + t];
    __syncthreads();
    float acc = 0.f;
    #pragma unroll 8
    for (int k = 0; k < DIN; ++k) acc = fmaf(xs[k], W1s[k * F1 + t], acc);
    h1[(size_t)ci * F1 + t] = acc;
    hs[t] = acc;
    __syncthreads();
    if (t < 8) {
      int h = t & 3;
      const float* att = (t < 4) ? att_s1 : att_d1;
      float s = 0.f;
      for (int c = 0; c < 32; ++c) s += hs[h * 32 + c] * att[h * 32 + c];
      if (t < 4) a1s[ci * 4 + h] = s; else a1d[ci * 4 + h] = s;
    }
    __syncthreads();
  }
}

__global__ void gat_e1max(int* ws) {
  int l1 = ws[O_CNT + 2]; if (l1 > L1CAP) l1 = L1CAP;
  float* a1s = (float*)(ws + O_A1S);
  float* a1d = (float*)(ws + O_A1D);
  float* m1  = (float*)(ws + O_M1);
  for (int i = blockIdx.x * blockDim.x + threadIdx.x; i < l1; i += gridDim.x * blockDim.x) {
    int s = ws[O_L1 + 2*i], d = ws[O_L1 + 2*i + 1];
    int ms = ws[O_MAP0 + s], md0 = ws[O_MAP0 + d], md1 = ws[O_MAP1 + d];
    if ((unsigned)ms >= C0CAP || (unsigned)md0 >= C0CAP || (unsigned)md1 >= C1CAP) continue;
    #pragma unroll
    for (int h = 0; h < 4; ++h) {
      float e = a1s[ms * 4 + h] + a1d[md0 * 4 + h];
      e = e > 0.f ? e : 0.2f * e;
      atomicMaxF(&m1[md1 * 4 + h], e);
    }
  }
}

// accumulate unnormalized sum: out1 += h[src]*exp(e-m), s1 += exp(e-m); divide later
__global__ void gat_e1sumagg(int* ws) {
  int l1 = ws[O_CNT + 2]; if (l1 > L1CAP) l1 = L1CAP;
  long total = (long)l1 * 32;
  float* a1s = (float*)(ws + O_A1S);
  float* a1d = (float*)(ws + O_A1D);
  float* m1  = (float*)(ws + O_M1);
  float* s1  = (float*)(ws + O_S1);
  float* h1  = (float*)(ws + O_H1);
  float* out1= (float*)(ws + O_OUT1);
  for (long idx = (long)blockIdx.x * blockDim.x + threadIdx.x; idx < total;
       idx += (long)gridDim.x * blockDim.x) {
    int i = (int)(idx >> 5), t = (int)(idx & 31);
    int s = ws[O_L1 + 2*i], d = ws[O_L1 + 2*i + 1];
    int ms = ws[O_MAP0 + s], md0 = ws[O_MAP0 + d], md1 = ws[O_MAP1 + d];
    if ((unsigned)ms >= C0CAP || (unsigned)md0 >= C0CAP || (unsigned)md1 >= C1CAP) continue;
    #pragma unroll
    for (int h = 0; h < 4; ++h) {
      float e = a1s[ms * 4 + h] + a1d[md0 * 4 + h];
      e = e > 0.f ? e : 0.2f * e;
      float w = expf(e - m1[md1 * 4 + h]);
      if (t == 0) atomicAdd(&s1[md1 * 4 + h], w);
      atomicAdd(&out1[md1 * F1 + h * 32 + t], h1[(size_t)ms * F1 + h * 32 + t] * w);
    }
  }
}

// finalize layer1 (divide, +bias1, ELU), layer-2 linear + attention scalars
__global__ void gat_l2prep(const float* __restrict__ b1, const float* __restrict__ W2,
                           const float* __restrict__ att_s2, const float* __restrict__ att_d2,
                           int* ws) {
  __shared__ float hs[F1];
  __shared__ float h2s[FOUT];
  int t = threadIdx.x;  // 128
  int c1 = ws[O_CNT + 0]; if (c1 > C1CAP) c1 = C1CAP;
  float* out1 = (float*)(ws + O_OUT1);
  float* s1   = (float*)(ws + O_S1);
  float* h2   = (float*)(ws + O_H2);
  float* a2s  = (float*)(ws + O_A2S);
  float* a2d  = (float*)(ws + O_A2D);
  for (int ci = blockIdx.x; ci < c1; ci += gridDim.x) {
    float hv = out1[ci * F1 + t] / (s1[ci * 4 + (t >> 5)] + 1e-16f) + b1[t];
    hv = hv > 0.f ? hv : (expf(hv) - 1.f);   // ELU
    hs[t] = hv;
    __syncthreads();
    if (t < FOUT) {
      float a = 0.f;
      for (int c = 0; c < F1; ++c) a = fmaf(hs[c], W2[c * FOUT + t], a);
      h2[ci * FOUT + t] = a;
      h2s[t] = a;
    }
    __syncthreads();
    if (t == 0) {
      float sa = 0.f, sd = 0.f;
      for (int o = 0; o < FOUT; ++o) { sa += h2s[o] * att_s2[o]; sd += h2s[o] * att_d2[o]; }
      a2s[ci] = sa; a2d[ci] = sd;
    }
    __syncthreads();
  }
}

__global__ void gat_e2max(int* ws) {
  int l2 = ws[O_CNT + 3]; if (l2 > L2CAP) l2 = L2CAP;
  float* a2s = (float*)(ws + O_A2S);
  float* a2d = (float*)(ws + O_A2D);
  float* m2  = (float*)(ws + O_M2);
  for (int i = blockIdx.x * blockDim.x + threadIdx.x; i < l2; i += gridDim.x * blockDim.x) {
    int s = ws[O_L2 + 2*i], d = ws[O_L2 + 2*i + 1];
    int msi = ws[O_MAP1 + s], mdi = ws[O_MAP1 + d];
    if ((unsigned)msi >= C1CAP || (unsigned)mdi >= C1CAP) continue;
    float e = a2s[msi] + a2d[mdi];
    e = e > 0.f ? e : 0.2f * e;
    atomicMaxF(&m2[mdi], e);
  }
}

__global__ void gat_e2sumagg(int* ws) {
  int l2 = ws[O_CNT + 3]; if (l2 > L2CAP) l2 = L2CAP;
  int total = l2 * FOUT;
  float* a2s = (float*)(ws + O_A2S);
  float* a2d = (float*)(ws + O_A2D);
  float* m2  = (float*)(ws + O_M2);
  float* s2  = (float*)(ws + O_S2);
  float* h2  = (float*)(ws + O_H2);
  float* out2= (float*)(ws + O_OUT2);
  for (int idx = blockIdx.x * blockDim.x + threadIdx.x; idx < total;
       idx += gridDim.x * blockDim.x) {
    int i = idx >> 4, o = idx & 15;
    int s = ws[O_L2 + 2*i], d = ws[O_L2 + 2*i + 1];
    int msi = ws[O_MAP1 + s], mdi = ws[O_MAP1 + d];
    if ((unsigned)msi >= C1CAP || (unsigned)mdi >= C1CAP) continue;
    float e = a2s[msi] + a2d[mdi];
    e = e > 0.f ? e : 0.2f * e;
    float w = expf(e - m2[mdi]);
    if (o == 0) atomicAdd(&s2[mdi], w);
    atomicAdd(&out2[mdi * FOUT + o], h2[msi * FOUT + o] * w);
  }
}

__global__ void gat_out(const float* __restrict__ b2, int* ws, float* __restrict__ out) {
  int i = blockIdx.x * blockDim.x + threadIdx.x;
  if (i >= GG * FOUT) return;
  int g = i >> 4, o = i & 15;
  int r = ws[O_ROOT + g];
  float val = 0.f;
  if (r < NN) {
    int ci = ws[O_MAP1 + r];
    if ((unsigned)ci < C1CAP) {
      float* out2 = (float*)(ws + O_OUT2);
      float* s2   = (float*)(ws + O_S2);
      val = out2[ci * FOUT + o] / (s2[ci] + 1e-16f);
    }
  }
  out[i] = val + b2[o];
}

extern "C" void kernel_launch(void* const* d_in, const int* in_sizes, int n_in,
                              void* d_out, int out_size, void* d_ws, size_t ws_size,
                              hipStream_t stream) {
  const float* x    = (const float*)d_in[0];
  const int*   ei   = (const int*)d_in[1];   // (2,E): [0:E)=src, [E:2E)=dst
  const int*   batch= (const int*)d_in[2];
  const float* W1   = (const float*)d_in[3];
  const float* as1  = (const float*)d_in[4];
  const float* ad1  = (const float*)d_in[5];
  const float* b1   = (const float*)d_in[6];
  const float* W2   = (const float*)d_in[7];
  const float* as2  = (const float*)d_in[8];
  const float* ad2  = (const float*)d_in[9];
  const float* b2   = (const float*)d_in[10];
  float* out = (float*)d_out;
  int* ws = (int*)d_ws;

  hipMemsetAsync(ws, 0, (size_t)O_ZEND * 4, stream);
  gat_init<<<(C1CAP * 4 + 255) / 256, 256, 0, stream>>>(ws);
  gat_roots<<<(NN + 255) / 256, 256, 0, stream>>>(x, batch, ws);
  gat_mark_roots<<<1, 128, 0, stream>>>(ws);
  gat_scan2<<<(EE + 255) / 256, 256, 0, stream>>>(ei, ws);
  gat_selfloop1<<<64, 256, 0, stream>>>(ws);
  gat_scan1<<<(EE + 255) / 256, 256, 0, stream>>>(ei, ws);
  gat_h1lin<<<1024, 128, 0, stream>>>(x, W1, as1, ad1, ws);
  gat_e1max<<<256, 256, 0, stream>>>(ws);
  gat_e1sumagg<<<2048, 256, 0, stream>>>(ws);
  gat_l2prep<<<512, 128, 0, stream>>>(b1, W2, as2, ad2, ws);
  gat_e2max<<<128, 256, 0, stream>>>(ws);
  gat_e2sumagg<<<128, 256, 0, stream>>>(ws);
  gat_out<<<(GG * FOUT + 255) / 256, 256, 0, stream>>>(b2, ws, out);
}

// Round 6
// 374.573 us; speedup vs baseline: 2.0018x; 2.0018x over previous
//
#include <hip/hip_runtime.h>
#include <math.h>

#define NN 100000
#define EE 1600000
#define GG 100
#define DIN 128
#define F1 128
#define FOUT 16

#define C1CAP 16384
#define C0CAP 49152
#define L1CAP 262144
#define L2CAP 32768

// ---- workspace layout (offsets in 4-byte words) ----
// zeroed region (single small memset):
#define O_CNT      0                        // 8 ints: [0]=c1,[1]=c0,[2]=l1,[3]=l2
#define O_FLAG1    (O_CNT + 8)              // int[NN]
#define O_FLAG0    (O_FLAG1 + NN)           // int[NN]
#define O_ISROOT   (O_FLAG0 + NN)           // int[NN]
#define O_ZEND     (O_ISROOT + NN)
// 0xFF-memset region:
#define O_ROOT     (O_ZEND)                 // uint[GG] (init 0xFFFFFFFF)
// written-before-read region:
#define O_MAP1     (O_ROOT + GG)            // int[NN]
#define O_MAP0     (O_MAP1 + NN)            // int[NN]
#define O_LIST1    (O_MAP0 + NN)            // int[C1CAP]
#define O_LIST0    (O_LIST1 + C1CAP)        // int[C0CAP]
#define O_L1       (O_LIST0 + C0CAP)        // int[L1CAP*2] (src,dst pairs)
#define O_L2       (O_L1 + L1CAP*2)         // int[L2CAP*2]
#define O_H1       (O_L2 + L2CAP*2)         // float[C0CAP*F1]
#define O_A1S      (O_H1 + C0CAP*F1)        // float[C0CAP*4]
#define O_A1D      (O_A1S + C0CAP*4)        // float[C0CAP*4]
#define O_H2       (O_A1D + C0CAP*4)        // float[C1CAP*FOUT]
#define O_A2S      (O_H2 + C1CAP*FOUT)      // float[C1CAP]
#define O_A2D      (O_A2S + C1CAP)          // float[C1CAP]
// zeroed by gat_selfloop1 up to actual c1 extent:
#define O_S1       (O_A2D + C1CAP)          // float[C1CAP*4]
#define O_S2       (O_S1 + C1CAP*4)         // float[C1CAP]
#define O_OUT1     (O_S2 + C1CAP)           // float[C1CAP*F1]
#define O_OUT2     (O_OUT1 + C1CAP*F1)      // float[C1CAP*FOUT]
#define O_END      (O_OUT2 + C1CAP*FOUT)

// ---- small-kernel claim helpers (low volume only) ----
__device__ __forceinline__ void claim1(int* ws, int node) {
  if (atomicCAS(&ws[O_FLAG1 + node], 0, 1) == 0) {
    int idx = atomicAdd(&ws[O_CNT + 0], 1);
    if (idx < C1CAP) { ws[O_MAP1 + node] = idx; ws[O_LIST1 + idx] = node; }
  }
}
__device__ __forceinline__ void claim0(int* ws, int node) {
  if (atomicCAS(&ws[O_FLAG0 + node], 0, 1) == 0) {
    int idx = atomicAdd(&ws[O_CNT + 1], 1);
    if (idx < C0CAP) { ws[O_MAP0 + node] = idx; ws[O_LIST0 + idx] = node; }
  }
}
__device__ __forceinline__ void appendL1(int* ws, int s, int d) {
  int idx = atomicAdd(&ws[O_CNT + 2], 1);
  if (idx < L1CAP) { ws[O_L1 + 2*idx] = s; ws[O_L1 + 2*idx + 1] = d; }
}
__device__ __forceinline__ void appendL2(int* ws, int s, int d) {
  int idx = atomicAdd(&ws[O_CNT + 3], 1);
  if (idx < L2CAP) { ws[O_L2 + 2*idx] = s; ws[O_L2 + 2*idx + 1] = d; }
}

// root of group g = min node index with x[:,0]==0 in that group
__global__ void gat_roots(const float* __restrict__ x, const int* __restrict__ batch, int* ws) {
  int i = blockIdx.x * blockDim.x + threadIdx.x;
  if (i >= NN) return;
  if (x[(size_t)i * DIN] == 0.f)
    atomicMin((unsigned int*)&ws[O_ROOT + batch[i]], (unsigned int)i);
}

__global__ void gat_mark_roots(int* ws) {
  int g = blockIdx.x * blockDim.x + threadIdx.x;
  if (g >= GG) return;
  unsigned int r = (unsigned int)ws[O_ROOT + g];
  if (r < NN) {
    ws[O_ISROOT + r] = 1;
    claim1(ws, (int)r);
    appendL2(ws, (int)r, (int)r);   // layer-2 self-loop
  }
}

// ---- LDS-aggregated edge scan: one global atomic per list per block ----
#define SBUF 2048
__global__ __launch_bounds__(256)
void gat_scan(const int* __restrict__ ei, int* __restrict__ ws,
              int probeOff, int cntPairIdx, int pairOff, int pairCap,
              int claimFlagOff, int cntClaimIdx, int mapOff, int listOff, int claimCap)
{
  __shared__ int sp[SBUF * 2];
  __shared__ int sc[SBUF];
  __shared__ int nP, nC, bP, bC;
  if (threadIdx.x == 0) { nP = 0; nC = 0; }
  __syncthreads();
  const int perBlock = (EE + gridDim.x - 1) / gridDim.x;
  const int beg = blockIdx.x * perBlock;
  const int end = min(beg + perBlock, EE);
  for (int ch = beg; ch < end; ch += 256) {
    int e = ch + threadIdx.x;
    if (e < end) {
      int d = ei[EE + e];
      if (ws[probeOff + d]) {
        int s = ei[e];
        int p = atomicAdd(&nP, 1);
        sp[2*p] = s; sp[2*p + 1] = d;
        if (atomicCAS(&ws[claimFlagOff + s], 0, 1) == 0)
          sc[atomicAdd(&nC, 1)] = s;
      }
    }
    __syncthreads();
    if (nP >= SBUF - 256 || nC >= SBUF - 256) {
      if (threadIdx.x == 0) {
        bP = atomicAdd(&ws[O_CNT + cntPairIdx], nP);
        bC = atomicAdd(&ws[O_CNT + cntClaimIdx], nC);
      }
      __syncthreads();
      for (int i = threadIdx.x; i < nP; i += 256) {
        int g = bP + i;
        if (g < pairCap) { ws[pairOff + 2*g] = sp[2*i]; ws[pairOff + 2*g + 1] = sp[2*i + 1]; }
      }
      for (int i = threadIdx.x; i < nC; i += 256) {
        int g = bC + i;
        if (g < claimCap) { int node = sc[i]; ws[mapOff + node] = g; ws[listOff + g] = node; }
      }
      __syncthreads();
      if (threadIdx.x == 0) { nP = 0; nC = 0; }
      __syncthreads();
    }
  }
  if (threadIdx.x == 0) {
    bP = atomicAdd(&ws[O_CNT + cntPairIdx], nP);
    bC = atomicAdd(&ws[O_CNT + cntClaimIdx], nC);
  }
  __syncthreads();
  for (int i = threadIdx.x; i < nP; i += 256) {
    int g = bP + i;
    if (g < pairCap) { ws[pairOff + 2*g] = sp[2*i]; ws[pairOff + 2*g + 1] = sp[2*i + 1]; }
  }
  for (int i = threadIdx.x; i < nC; i += 256) {
    int g = bC + i;
    if (g < claimCap) { int node = sc[i]; ws[mapOff + node] = g; ws[listOff + g] = node; }
  }
}

// self-loops for S1 nodes + claim them into S0; also zero the accumulators
// to the actual c1 extent (avoids an 11 MB cap-sized memset)
__global__ void gat_selfloop1(int* ws) {
  int c1 = ws[O_CNT + 0]; if (c1 > C1CAP) c1 = C1CAP;
  int stride = gridDim.x * blockDim.x;
  int t0 = blockIdx.x * blockDim.x + threadIdx.x;
  for (int i = t0; i < c1; i += stride) {
    int v = ws[O_LIST1 + i];
    appendL1(ws, v, v);
    claim0(ws, v);
  }
  float* s1   = (float*)(ws + O_S1);
  float* s2   = (float*)(ws + O_S2);
  float* out1 = (float*)(ws + O_OUT1);
  float* out2 = (float*)(ws + O_OUT2);
  for (int i = t0; i < c1 * F1; i += stride) out1[i] = 0.f;
  for (int i = t0; i < c1 * FOUT; i += stride) out2[i] = 0.f;
  for (int i = t0; i < c1 * 4; i += stride) s1[i] = 0.f;
  for (int i = t0; i < c1; i += stride) s2[i] = 0.f;
}

// h1lin = x@W1 at need0 nodes; also a_src1/a_dst1 per head
__global__ void gat_h1lin(const float* __restrict__ x, const float* __restrict__ W1,
                          const float* __restrict__ att_s1, const float* __restrict__ att_d1,
                          int* ws) {
  __shared__ float W1s[DIN * F1];   // 64 KiB
  __shared__ float xs[DIN];
  __shared__ float hs[F1];
  int t = threadIdx.x;  // 128
  for (int i = t; i < DIN * F1; i += blockDim.x) W1s[i] = W1[i];
  __syncthreads();
  int c0 = ws[O_CNT + 1]; if (c0 > C0CAP) c0 = C0CAP;
  float* h1  = (float*)(ws + O_H1);
  float* a1s = (float*)(ws + O_A1S);
  float* a1d = (float*)(ws + O_A1D);
  for (int ci = blockIdx.x; ci < c0; ci += gridDim.x) {
    int v = ws[O_LIST0 + ci];
    xs[t] = x[(size_t)v * DIN + t];
    __syncthreads();
    float acc = 0.f;
    #pragma unroll 8
    for (int k = 0; k < DIN; ++k) acc = fmaf(xs[k], W1s[k * F1 + t], acc);
    h1[(size_t)ci * F1 + t] = acc;
    hs[t] = acc;
    __syncthreads();
    if (t < 8) {
      int h = t & 3;
      const float* att = (t < 4) ? att_s1 : att_d1;
      float s = 0.f;
      for (int c = 0; c < 32; ++c) s += hs[h * 32 + c] * att[h * 32 + c];
      if (t < 4) a1s[ci * 4 + h] = s; else a1d[ci * 4 + h] = s;
    }
    __syncthreads();
  }
}

// accumulate unnormalized: out1 += h[src]*exp(e), s1 += exp(e); divide later.
// (no max-subtraction: alpha = exp(e)/sum exp(e) is scale-invariant and |e|<~5)
__global__ void gat_e1sumagg(int* ws) {
  int l1 = ws[O_CNT + 2]; if (l1 > L1CAP) l1 = L1CAP;
  long total = (long)l1 * 32;
  float* a1s = (float*)(ws + O_A1S);
  float* a1d = (float*)(ws + O_A1D);
  float* s1  = (float*)(ws + O_S1);
  float* h1  = (float*)(ws + O_H1);
  float* out1= (float*)(ws + O_OUT1);
  for (long idx = (long)blockIdx.x * blockDim.x + threadIdx.x; idx < total;
       idx += (long)gridDim.x * blockDim.x) {
    int i = (int)(idx >> 5), t = (int)(idx & 31);
    int s = ws[O_L1 + 2*i], d = ws[O_L1 + 2*i + 1];
    int ms = ws[O_MAP0 + s], md0 = ws[O_MAP0 + d], md1 = ws[O_MAP1 + d];
    if ((unsigned)ms >= C0CAP || (unsigned)md0 >= C0CAP || (unsigned)md1 >= C1CAP) continue;
    #pragma unroll
    for (int h = 0; h < 4; ++h) {
      float e = a1s[ms * 4 + h] + a1d[md0 * 4 + h];
      e = e > 0.f ? e : 0.2f * e;
      float w = expf(e);
      if (t == 0) atomicAdd(&s1[md1 * 4 + h], w);
      atomicAdd(&out1[md1 * F1 + h * 32 + t], h1[(size_t)ms * F1 + h * 32 + t] * w);
    }
  }
}

// finalize layer1 (divide, +bias1, ELU), layer-2 linear + attention scalars
__global__ void gat_l2prep(const float* __restrict__ b1, const float* __restrict__ W2,
                           const float* __restrict__ att_s2, const float* __restrict__ att_d2,
                           int* ws) {
  __shared__ float hs[F1];
  __shared__ float h2s[FOUT];
  int t = threadIdx.x;  // 128
  int c1 = ws[O_CNT + 0]; if (c1 > C1CAP) c1 = C1CAP;
  float* out1 = (float*)(ws + O_OUT1);
  float* s1   = (float*)(ws + O_S1);
  float* h2   = (float*)(ws + O_H2);
  float* a2s  = (float*)(ws + O_A2S);
  float* a2d  = (float*)(ws + O_A2D);
  for (int ci = blockIdx.x; ci < c1; ci += gridDim.x) {
    float hv = out1[ci * F1 + t] / (s1[ci * 4 + (t >> 5)] + 1e-16f) + b1[t];
    hv = hv > 0.f ? hv : (expf(hv) - 1.f);   // ELU
    hs[t] = hv;
    __syncthreads();
    if (t < FOUT) {
      float a = 0.f;
      for (int c = 0; c < F1; ++c) a = fmaf(hs[c], W2[c * FOUT + t], a);
      h2[ci * FOUT + t] = a;
      h2s[t] = a;
    }
    __syncthreads();
    if (t == 0) {
      float sa = 0.f, sd = 0.f;
      for (int o = 0; o < FOUT; ++o) { sa += h2s[o] * att_s2[o]; sd += h2s[o] * att_d2[o]; }
      a2s[ci] = sa; a2d[ci] = sd;
    }
    __syncthreads();
  }
}

__global__ void gat_e2sumagg(int* ws) {
  int l2 = ws[O_CNT + 3]; if (l2 > L2CAP) l2 = L2CAP;
  int total = l2 * FOUT;
  float* a2s = (float*)(ws + O_A2S);
  float* a2d = (float*)(ws + O_A2D);
  float* s2  = (float*)(ws + O_S2);
  float* h2  = (float*)(ws + O_H2);
  float* out2= (float*)(ws + O_OUT2);
  for (int idx = blockIdx.x * blockDim.x + threadIdx.x; idx < total;
       idx += gridDim.x * blockDim.x) {
    int i = idx >> 4, o = idx & 15;
    int s = ws[O_L2 + 2*i], d = ws[O_L2 + 2*i + 1];
    int msi = ws[O_MAP1 + s], mdi = ws[O_MAP1 + d];
    if ((unsigned)msi >= C1CAP || (unsigned)mdi >= C1CAP) continue;
    float e = a2s[msi] + a2d[mdi];
    e = e > 0.f ? e : 0.2f * e;
    float w = expf(e);
    if (o == 0) atomicAdd(&s2[mdi], w);
    atomicAdd(&out2[mdi * FOUT + o], h2[msi * FOUT + o] * w);
  }
}

__global__ void gat_out(const float* __restrict__ b2, int* ws, float* __restrict__ out) {
  int i = blockIdx.x * blockDim.x + threadIdx.x;
  if (i >= GG * FOUT) return;
  int g = i >> 4, o = i & 15;
  unsigned int r = (unsigned int)ws[O_ROOT + g];
  float val = 0.f;
  if (r < NN) {
    int ci = ws[O_MAP1 + r];
    if ((unsigned)ci < C1CAP) {
      float* out2 = (float*)(ws + O_OUT2);
      float* s2   = (float*)(ws + O_S2);
      val = out2[ci * FOUT + o] / (s2[ci] + 1e-16f);
    }
  }
  out[i] = val + b2[o];
}

extern "C" void kernel_launch(void* const* d_in, const int* in_sizes, int n_in,
                              void* d_out, int out_size, void* d_ws, size_t ws_size,
                              hipStream_t stream) {
  const float* x    = (const float*)d_in[0];
  const int*   ei   = (const int*)d_in[1];   // (2,E): [0:E)=src, [E:2E)=dst
  const int*   batch= (const int*)d_in[2];
  const float* W1   = (const float*)d_in[3];
  const float* as1  = (const float*)d_in[4];
  const float* ad1  = (const float*)d_in[5];
  const float* b1   = (const float*)d_in[6];
  const float* W2   = (const float*)d_in[7];
  const float* as2  = (const float*)d_in[8];
  const float* ad2  = (const float*)d_in[9];
  const float* b2   = (const float*)d_in[10];
  float* out = (float*)d_out;
  int* ws = (int*)d_ws;

  hipMemsetAsync(ws, 0, (size_t)O_ZEND * 4, stream);
  hipMemsetAsync(ws + O_ROOT, 0xFF, (size_t)GG * 4, stream);
  gat_roots<<<(NN + 255) / 256, 256, 0, stream>>>(x, batch, ws);
  gat_mark_roots<<<1, 128, 0, stream>>>(ws);
  gat_scan<<<1024, 256, 0, stream>>>(ei, ws,
      O_ISROOT, 3, O_L2, L2CAP, O_FLAG1, 0, O_MAP1, O_LIST1, C1CAP);
  gat_selfloop1<<<64, 256, 0, stream>>>(ws);
  gat_scan<<<1024, 256, 0, stream>>>(ei, ws,
      O_FLAG1, 2, O_L1, L1CAP, O_FLAG0, 1, O_MAP0, O_LIST0, C0CAP);
  gat_h1lin<<<1024, 128, 0, stream>>>(x, W1, as1, ad1, ws);
  gat_e1sumagg<<<2048, 256, 0, stream>>>(ws);
  gat_l2prep<<<512, 128, 0, stream>>>(b1, W2, as2, ad2, ws);
  gat_e2sumagg<<<128, 256, 0, stream>>>(ws);
  gat_out<<<(GG * FOUT + 255) / 256, 256, 0, stream>>>(b2, ws, out);
}

// Round 7
// 253.742 us; speedup vs baseline: 2.9551x; 1.4762x over previous
//
#include <hip/hip_runtime.h>
#include <math.h>

#define NN 100000
#define EE 1600000
#define GG 100
#define DIN 128
#define F1 128
#define FOUT 16

#define C1CAP 16384
#define C0CAP 49152
#define L1CAP 262144
#define L2CAP 32768
#define NT 16   // nodes per h1lin tile

// ---- workspace layout (offsets in 4-byte words) ----
// zeroed region (single small memset):
#define O_CNT      0                        // 8 ints: [0]=c1,[1]=c0,[2]=l1,[3]=l2
#define O_FLAG1    (O_CNT + 8)              // int[NN]
#define O_FLAG0    (O_FLAG1 + NN)           // int[NN]
#define O_ISROOT   (O_FLAG0 + NN)           // int[NN]
#define O_FILL     (O_ISROOT + NN)          // int[C1CAP] histogram/fill counters
#define O_ZEND     (O_FILL + C1CAP)
// 0xFF-memset region:
#define O_ROOT     (O_ZEND)                 // uint[GG]
// written-before-read region:
#define O_MAP1     (O_ROOT + GG)            // int[NN]
#define O_MAP0     (O_MAP1 + NN)            // int[NN]
#define O_LIST1    (O_MAP0 + NN)            // int[C1CAP]
#define O_LIST0    (O_LIST1 + C1CAP)        // int[C0CAP]
#define O_L1       (O_LIST0 + C0CAP)        // int[L1CAP*2] (src,dst)
#define O_L2       (O_L1 + L1CAP*2)         // int[L2CAP*2]
#define O_CSRP     (O_L2 + L2CAP*2)         // int[C1CAP+1] CSR row ptr
#define O_ORDER    (O_CSRP + C1CAP + 1)     // int[L1CAP] edge permutation
#define O_H1       (O_ORDER + L1CAP)        // float[C0CAP*F1]
#define O_A1S      (O_H1 + C0CAP*F1)        // float[C0CAP*4]
#define O_A1D      (O_A1S + C0CAP*4)        // float[C0CAP*4]
#define O_H2       (O_A1D + C0CAP*4)        // float[C1CAP*FOUT]
#define O_A2S      (O_H2 + C1CAP*FOUT)      // float[C1CAP]
#define O_A2D      (O_A2S + C1CAP)          // float[C1CAP]
#define O_S1       (O_A2D + C1CAP)          // float[C1CAP*4]  (written by e1agg)
#define O_OUT1     (O_S1 + C1CAP*4)         // float[C1CAP*F1] (written by e1agg)
#define O_S2       (O_OUT1 + C1CAP*F1)      // float[C1CAP]    (zeroed by selfloop1)
#define O_OUT2     (O_S2 + C1CAP)           // float[C1CAP*FOUT] (zeroed by selfloop1)
#define O_END      (O_OUT2 + C1CAP*FOUT)

// ---- claim helpers (low volume only) ----
__device__ __forceinline__ void claim1(int* ws, int node) {
  if (atomicCAS(&ws[O_FLAG1 + node], 0, 1) == 0) {
    int idx = atomicAdd(&ws[O_CNT + 0], 1);
    if (idx < C1CAP) { ws[O_MAP1 + node] = idx; ws[O_LIST1 + idx] = node; }
  }
}
__device__ __forceinline__ void claim0(int* ws, int node) {
  if (atomicCAS(&ws[O_FLAG0 + node], 0, 1) == 0) {
    int idx = atomicAdd(&ws[O_CNT + 1], 1);
    if (idx < C0CAP) { ws[O_MAP0 + node] = idx; ws[O_LIST0 + idx] = node; }
  }
}
__device__ __forceinline__ void appendL1(int* ws, int s, int d) {
  int idx = atomicAdd(&ws[O_CNT + 2], 1);
  if (idx < L1CAP) { ws[O_L1 + 2*idx] = s; ws[O_L1 + 2*idx + 1] = d; }
}
__device__ __forceinline__ void appendL2(int* ws, int s, int d) {
  int idx = atomicAdd(&ws[O_CNT + 3], 1);
  if (idx < L2CAP) { ws[O_L2 + 2*idx] = s; ws[O_L2 + 2*idx + 1] = d; }
}

// root of group g = min node index with x[:,0]==0
__global__ void gat_roots(const float* __restrict__ x, const int* __restrict__ batch, int* ws) {
  int i = blockIdx.x * blockDim.x + threadIdx.x;
  if (i >= NN) return;
  if (x[(size_t)i * DIN] == 0.f)
    atomicMin((unsigned int*)&ws[O_ROOT + batch[i]], (unsigned int)i);
}

__global__ void gat_mark_roots(int* ws) {
  int g = blockIdx.x * blockDim.x + threadIdx.x;
  if (g >= GG) return;
  unsigned int r = (unsigned int)ws[O_ROOT + g];
  if (r < NN) {
    ws[O_ISROOT + r] = 1;
    claim1(ws, (int)r);
    appendL2(ws, (int)r, (int)r);
  }
}

// ---- LDS-aggregated edge scan (round-1 version, measured good) ----
#define SBUF 2048
__global__ __launch_bounds__(256)
void gat_scan(const int* __restrict__ ei, int* __restrict__ ws,
              int probeOff, int cntPairIdx, int pairOff, int pairCap,
              int claimFlagOff, int cntClaimIdx, int mapOff, int listOff, int claimCap)
{
  __shared__ int sp[SBUF * 2];
  __shared__ int sc[SBUF];
  __shared__ int nP, nC, bP, bC;
  if (threadIdx.x == 0) { nP = 0; nC = 0; }
  __syncthreads();
  const int perBlock = (EE + gridDim.x - 1) / gridDim.x;
  const int beg = blockIdx.x * perBlock;
  const int end = min(beg + perBlock, EE);
  for (int ch = beg; ch < end; ch += 256) {
    int e = ch + threadIdx.x;
    if (e < end) {
      int d = ei[EE + e];
      if (ws[probeOff + d]) {
        int s = ei[e];
        int p = atomicAdd(&nP, 1);
        sp[2*p] = s; sp[2*p + 1] = d;
        if (atomicCAS(&ws[claimFlagOff + s], 0, 1) == 0)
          sc[atomicAdd(&nC, 1)] = s;
      }
    }
    __syncthreads();
    if (nP >= SBUF - 256 || nC >= SBUF - 256) {
      if (threadIdx.x == 0) {
        bP = atomicAdd(&ws[O_CNT + cntPairIdx], nP);
        bC = atomicAdd(&ws[O_CNT + cntClaimIdx], nC);
      }
      __syncthreads();
      for (int i = threadIdx.x; i < nP; i += 256) {
        int g = bP + i;
        if (g < pairCap) { ws[pairOff + 2*g] = sp[2*i]; ws[pairOff + 2*g + 1] = sp[2*i + 1]; }
      }
      for (int i = threadIdx.x; i < nC; i += 256) {
        int g = bC + i;
        if (g < claimCap) { int node = sc[i]; ws[mapOff + node] = g; ws[listOff + g] = node; }
      }
      __syncthreads();
      if (threadIdx.x == 0) { nP = 0; nC = 0; }
      __syncthreads();
    }
  }
  if (threadIdx.x == 0) {
    bP = atomicAdd(&ws[O_CNT + cntPairIdx], nP);
    bC = atomicAdd(&ws[O_CNT + cntClaimIdx], nC);
  }
  __syncthreads();
  for (int i = threadIdx.x; i < nP; i += 256) {
    int g = bP + i;
    if (g < pairCap) { ws[pairOff + 2*g] = sp[2*i]; ws[pairOff + 2*g + 1] = sp[2*i + 1]; }
  }
  for (int i = threadIdx.x; i < nC; i += 256) {
    int g = bC + i;
    if (g < claimCap) { int node = sc[i]; ws[mapOff + node] = g; ws[listOff + g] = node; }
  }
}

// self-loops for S1 nodes + claim into S0; zero e2 accumulators to c1 extent
__global__ void gat_selfloop1(int* ws) {
  int c1 = ws[O_CNT + 0]; if (c1 > C1CAP) c1 = C1CAP;
  int stride = gridDim.x * blockDim.x;
  int t0 = blockIdx.x * blockDim.x + threadIdx.x;
  for (int i = t0; i < c1; i += stride) {
    int v = ws[O_LIST1 + i];
    appendL1(ws, v, v);
    claim0(ws, v);
  }
  float* s2   = (float*)(ws + O_S2);
  float* out2 = (float*)(ws + O_OUT2);
  for (int i = t0; i < c1 * FOUT; i += stride) out2[i] = 0.f;
  for (int i = t0; i < c1; i += stride) s2[i] = 0.f;
}

// h1lin v2: 16-node tiles, x-tile in LDS (8 KB), W1 streamed from global (L1/L2),
// each thread: 8 nodes x 1 col, float4 broadcast LDS reads. att dots via shfl.
__global__ __launch_bounds__(256) void gat_h1lin(
    const float* __restrict__ x, const float* __restrict__ W1,
    const float* __restrict__ att_s1, const float* __restrict__ att_d1, int* ws) {
  __shared__ float xs[NT][DIN];   // 8 KB
  int t = threadIdx.x, col = t & 127, half = t >> 7;
  int c0 = ws[O_CNT + 1]; if (c0 > C0CAP) c0 = C0CAP;
  float* h1  = (float*)(ws + O_H1);
  float* a1s = (float*)(ws + O_A1S);
  float* a1d = (float*)(ws + O_A1D);
  float as1v = att_s1[col], ad1v = att_d1[col];  // (H,HID) layout => index == col
  for (int tile = blockIdx.x * NT; tile < c0; tile += gridDim.x * NT) {
    // stage x tile: thread t loads node n=t>>4, 8 floats at k0=(t&15)*8
    {
      int n = t >> 4, k0 = (t & 15) * 8;
      int ci = tile + n;
      if (ci < c0) {
        int v = ws[O_LIST0 + ci];
        const float4* src = (const float4*)&x[(size_t)v * DIN + k0];
        *(float4*)&xs[n][k0]     = src[0];
        *(float4*)&xs[n][k0 + 4] = src[1];
      }
    }
    __syncthreads();
    float acc[8];
    #pragma unroll
    for (int i = 0; i < 8; ++i) acc[i] = 0.f;
    #pragma unroll 4
    for (int k = 0; k < DIN; k += 4) {
      float w0 = W1[(k + 0) * F1 + col];
      float w1 = W1[(k + 1) * F1 + col];
      float w2 = W1[(k + 2) * F1 + col];
      float w3 = W1[(k + 3) * F1 + col];
      #pragma unroll
      for (int n8 = 0; n8 < 8; ++n8) {
        const float4 xv = *(const float4*)&xs[half * 8 + n8][k];
        acc[n8] = fmaf(xv.x, w0, acc[n8]);
        acc[n8] = fmaf(xv.y, w1, acc[n8]);
        acc[n8] = fmaf(xv.z, w2, acc[n8]);
        acc[n8] = fmaf(xv.w, w3, acc[n8]);
      }
    }
    #pragma unroll
    for (int n8 = 0; n8 < 8; ++n8) {
      int ci = tile + half * 8 + n8;
      bool ok = ci < c0;
      if (ok) h1[(size_t)ci * F1 + col] = acc[n8];
      float cs = acc[n8] * as1v, cd = acc[n8] * ad1v;
      #pragma unroll
      for (int off = 16; off > 0; off >>= 1) {
        cs += __shfl_down(cs, off, 32);
        cd += __shfl_down(cd, off, 32);
      }
      if (ok && (col & 31) == 0) {
        a1s[ci * 4 + (col >> 5)] = cs;
        a1d[ci * 4 + (col >> 5)] = cd;
      }
    }
    __syncthreads();  // xs reused next tile
  }
}

// ---- CSR build for layer-1 edges (group by dst) ----
__global__ void gat_e1hist(int* ws) {
  int l1 = ws[O_CNT + 2]; if (l1 > L1CAP) l1 = L1CAP;
  for (int i = blockIdx.x * blockDim.x + threadIdx.x; i < l1; i += gridDim.x * blockDim.x) {
    int d = ws[O_L1 + 2*i + 1];
    int md1 = ws[O_MAP1 + d];
    if ((unsigned)md1 < C1CAP) atomicAdd(&ws[O_FILL + md1], 1);
  }
}

__global__ __launch_bounds__(256) void gat_e1scan(int* ws) {
  __shared__ int part[256];
  int n = ws[O_CNT + 0]; if (n > C1CAP) n = C1CAP;   // c1 rows
  int t = threadIdx.x;
  int chunk = (n + 255) >> 8;
  int b = t * chunk, e = min(b + chunk, n);
  int s = 0;
  for (int i = b; i < e; ++i) s += ws[O_FILL + i];
  part[t] = s;
  __syncthreads();
  for (int off = 1; off < 256; off <<= 1) {
    int v = (t >= off) ? part[t - off] : 0;
    __syncthreads();
    part[t] += v;
    __syncthreads();
  }
  int base = (t == 0) ? 0 : part[t - 1];
  for (int i = b; i < e; ++i) {
    int c = ws[O_FILL + i];
    ws[O_CSRP + i] = base;
    base += c;
    ws[O_FILL + i] = 0;   // reset for scatter
  }
  if (t == 0) ws[O_CSRP + n] = part[255];
}

__global__ void gat_e1scatter(int* ws) {
  int l1 = ws[O_CNT + 2]; if (l1 > L1CAP) l1 = L1CAP;
  for (int i = blockIdx.x * blockDim.x + threadIdx.x; i < l1; i += gridDim.x * blockDim.x) {
    int d = ws[O_L1 + 2*i + 1];
    int md1 = ws[O_MAP1 + d];
    if ((unsigned)md1 >= C1CAP) continue;
    int pos = ws[O_CSRP + md1] + atomicAdd(&ws[O_FILL + md1], 1);
    if (pos < L1CAP) ws[O_ORDER + pos] = i;
  }
}

// layer-1 aggregation, CSR: one block per dst, no global atomics
__global__ __launch_bounds__(256) void gat_e1agg(int* ws) {
  int c1 = ws[O_CNT + 0]; if (c1 > C1CAP) c1 = C1CAP;
  float* a1s  = (float*)(ws + O_A1S);
  float* a1d  = (float*)(ws + O_A1D);
  float* h1   = (float*)(ws + O_H1);
  float* out1 = (float*)(ws + O_OUT1);
  float* s1   = (float*)(ws + O_S1);
  __shared__ int   msBuf[256];
  __shared__ float wBuf[256 * 4];
  __shared__ float sacc[2][F1];
  int t = threadIdx.x, col = t & 127, half = t >> 7;
  for (int ci = blockIdx.x; ci < c1; ci += gridDim.x) {
    int beg = ws[O_CSRP + ci], end = ws[O_CSRP + ci + 1];
    int node = ws[O_LIST1 + ci];
    int md0 = ws[O_MAP0 + node];
    if ((unsigned)md0 >= C0CAP) md0 = 0;
    float acc = 0.f;
    float sh  = 0.f;   // valid for t<4: sum of w for head t
    for (int cb = beg; cb < end; cb += 256) {
      int cnt = min(256, end - cb);
      __syncthreads();
      if (t < cnt) {
        int e = ws[O_ORDER + cb + t];
        int srcn = ws[O_L1 + 2*e];
        int ms = ws[O_MAP0 + srcn];
        if ((unsigned)ms >= C0CAP) ms = 0;
        msBuf[t] = ms;
        #pragma unroll
        for (int h = 0; h < 4; ++h) {
          float ev = a1s[ms * 4 + h] + a1d[md0 * 4 + h];
          ev = ev > 0.f ? ev : 0.2f * ev;
          wBuf[t * 4 + h] = __expf(ev);
        }
      }
      __syncthreads();
      for (int j = half; j < cnt; j += 2) {
        int ms = msBuf[j];
        float w = wBuf[j * 4 + (col >> 5)];
        acc = fmaf(h1[(size_t)ms * F1 + col], w, acc);
      }
      if (t < 4) for (int j = 0; j < cnt; ++j) sh += wBuf[j * 4 + t];
    }
    sacc[half][col] = acc;
    __syncthreads();
    if (half == 0) out1[(size_t)ci * F1 + col] = sacc[0][col] + sacc[1][col];
    if (t < 4) s1[ci * 4 + t] = sh;
    __syncthreads();
  }
}

// finalize layer1 (divide, +bias1, ELU), layer-2 linear + attention scalars
__global__ void gat_l2prep(const float* __restrict__ b1, const float* __restrict__ W2,
                           const float* __restrict__ att_s2, const float* __restrict__ att_d2,
                           int* ws) {
  __shared__ float hs[F1];
  __shared__ float h2s[FOUT];
  int t = threadIdx.x;  // 128
  int c1 = ws[O_CNT + 0]; if (c1 > C1CAP) c1 = C1CAP;
  float* out1 = (float*)(ws + O_OUT1);
  float* s1   = (float*)(ws + O_S1);
  float* h2   = (float*)(ws + O_H2);
  float* a2s  = (float*)(ws + O_A2S);
  float* a2d  = (float*)(ws + O_A2D);
  for (int ci = blockIdx.x; ci < c1; ci += gridDim.x) {
    float hv = out1[(size_t)ci * F1 + t] / (s1[ci * 4 + (t >> 5)] + 1e-16f) + b1[t];
    hv = hv > 0.f ? hv : (expf(hv) - 1.f);   // ELU
    hs[t] = hv;
    __syncthreads();
    if (t < FOUT) {
      float a = 0.f;
      for (int c = 0; c < F1; ++c) a = fmaf(hs[c], W2[c * FOUT + t], a);
      h2[ci * FOUT + t] = a;
      h2s[t] = a;
    }
    __syncthreads();
    if (t == 0) {
      float sa = 0.f, sd = 0.f;
      for (int o = 0; o < FOUT; ++o) { sa += h2s[o] * att_s2[o]; sd += h2s[o] * att_d2[o]; }
      a2s[ci] = sa; a2d[ci] = sd;
    }
    __syncthreads();
  }
}

__global__ void gat_e2sumagg(int* ws) {
  int l2 = ws[O_CNT + 3]; if (l2 > L2CAP) l2 = L2CAP;
  int total = l2 * FOUT;
  float* a2s = (float*)(ws + O_A2S);
  float* a2d = (float*)(ws + O_A2D);
  float* s2  = (float*)(ws + O_S2);
  float* h2  = (float*)(ws + O_H2);
  float* out2= (float*)(ws + O_OUT2);
  for (int idx = blockIdx.x * blockDim.x + threadIdx.x; idx < total;
       idx += gridDim.x * blockDim.x) {
    int i = idx >> 4, o = idx & 15;
    int s = ws[O_L2 + 2*i], d = ws[O_L2 + 2*i + 1];
    int msi = ws[O_MAP1 + s], mdi = ws[O_MAP1 + d];
    if ((unsigned)msi >= C1CAP || (unsigned)mdi >= C1CAP) continue;
    float e = a2s[msi] + a2d[mdi];
    e = e > 0.f ? e : 0.2f * e;
    float w = expf(e);
    if (o == 0) atomicAdd(&s2[mdi], w);
    atomicAdd(&out2[mdi * FOUT + o], h2[msi * FOUT + o] * w);
  }
}

__global__ void gat_out(const float* __restrict__ b2, int* ws, float* __restrict__ out) {
  int i = blockIdx.x * blockDim.x + threadIdx.x;
  if (i >= GG * FOUT) return;
  int g = i >> 4, o = i & 15;
  unsigned int r = (unsigned int)ws[O_ROOT + g];
  float val = 0.f;
  if (r < NN) {
    int ci = ws[O_MAP1 + r];
    if ((unsigned)ci < C1CAP) {
      float* out2 = (float*)(ws + O_OUT2);
      float* s2   = (float*)(ws + O_S2);
      val = out2[ci * FOUT + o] / (s2[ci] + 1e-16f);
    }
  }
  out[i] = val + b2[o];
}

extern "C" void kernel_launch(void* const* d_in, const int* in_sizes, int n_in,
                              void* d_out, int out_size, void* d_ws, size_t ws_size,
                              hipStream_t stream) {
  const float* x    = (const float*)d_in[0];
  const int*   ei   = (const int*)d_in[1];   // (2,E)
  const int*   batch= (const int*)d_in[2];
  const float* W1   = (const float*)d_in[3];
  const float* as1  = (const float*)d_in[4];
  const float* ad1  = (const float*)d_in[5];
  const float* b1   = (const float*)d_in[6];
  const float* W2   = (const float*)d_in[7];
  const float* as2  = (const float*)d_in[8];
  const float* ad2  = (const float*)d_in[9];
  const float* b2   = (const float*)d_in[10];
  float* out = (float*)d_out;
  int* ws = (int*)d_ws;

  hipMemsetAsync(ws, 0, (size_t)O_ZEND * 4, stream);
  hipMemsetAsync(ws + O_ROOT, 0xFF, (size_t)GG * 4, stream);
  gat_roots<<<(NN + 255) / 256, 256, 0, stream>>>(x, batch, ws);
  gat_mark_roots<<<1, 128, 0, stream>>>(ws);
  gat_scan<<<1024, 256, 0, stream>>>(ei, ws,
      O_ISROOT, 3, O_L2, L2CAP, O_FLAG1, 0, O_MAP1, O_LIST1, C1CAP);
  gat_selfloop1<<<64, 256, 0, stream>>>(ws);
  gat_scan<<<1024, 256, 0, stream>>>(ei, ws,
      O_FLAG1, 2, O_L1, L1CAP, O_FLAG0, 1, O_MAP0, O_LIST0, C0CAP);
  gat_h1lin<<<C0CAP / NT, 256, 0, stream>>>(x, W1, as1, ad1, ws);
  gat_e1hist<<<128, 256, 0, stream>>>(ws);
  gat_e1scan<<<1, 256, 0, stream>>>(ws);
  gat_e1scatter<<<128, 256, 0, stream>>>(ws);
  gat_e1agg<<<2048, 256, 0, stream>>>(ws);
  gat_l2prep<<<512, 128, 0, stream>>>(b1, W2, as2, ad2, ws);
  gat_e2sumagg<<<128, 256, 0, stream>>>(ws);
  gat_out<<<(GG * FOUT + 255) / 256, 256, 0, stream>>>(b2, ws, out);
}